// Round 1
// 73.591 us; speedup vs baseline: 1.0505x; 1.0505x over previous
//
#include <hip/hip_runtime.h>

#define NROT 256
#define NB   8192
#define TBL_ROUNDS 264   // 255 real rounds + identity padding for prefetch ring

// ---------------------------------------------------------------------------
// Workspace layout (bytes):
//   [0,       540672)   cs/ij table: 264 rounds x 128 x float4
//   [540672, 1589248)   Rg: 4 group products (4 x 256x256 f32)
//   [1589248,2113536)   M : 2 level-1 merged products
//   [2113536,2375680)   R : final merged 256x256 f32
// ---------------------------------------------------------------------------

// ---------------------------------------------------------------------------
// K1: build per-(round,pair) table: {cos, sin, packed (i | j<<16), 0}
// Rounds >= 255 are identity padding (c=1, s=0, pair (0,1)) -> exact no-op.
// ---------------------------------------------------------------------------
__global__ void k_prep(const float* __restrict__ thetas, float4* __restrict__ tbl) {
    int idx = blockIdx.x * 256 + threadIdx.x;
    if (idx >= TBL_ROUNDS * 128) return;
    int r = idx >> 7;
    int k = idx & 127;
    if (r >= 255) {
        tbl[idx] = make_float4(1.0f, 0.0f, __int_as_float(0 | (1 << 16)), 0.0f);
        return;
    }
    int i, j;
    if (k == 0) {
        i = 0;
        j = (254 - r) + 1;
    } else {
        int m1 = k - 1 - r;   if (m1 < 0) m1 += 255;
        int m2 = 254 - k - r; if (m2 < 0) m2 += 255;
        int v1 = m1 + 1, v2 = m2 + 1;
        i = v1 < v2 ? v1 : v2;
        j = v1 < v2 ? v2 : v1;
    }
    int tix = i * 256 - (i * (i + 1)) / 2 + (j - i - 1);
    float th = thetas[tix];
    float s, c;
    sincosf(th, &s, &c);
    tbl[idx] = make_float4(c, s, __int_as_float(i | (j << 16)), 0.0f);
}

// ---------------------------------------------------------------------------
// K2: partial rotation products, 4 groups of 64 rounds (round 255 = pad no-op).
// One wave per block, 4 columns in LDS, wave-synchronous (no barriers).
// Depth-4 register prefetch ring (64 % 4 == 0 -> static ring slot).
// ---------------------------------------------------------------------------
template <int ROFF>
__device__ __forceinline__ void rot_rounds64(const float4* __restrict__ t0, float4* buf) {
    float4 e0[4], e1[4];
#pragma unroll
    for (int d = 0; d < 4; ++d) {
        e0[d] = t0[(ROFF + d) * 128];
        e1[d] = t0[(ROFF + d) * 128 + 1];
    }
#pragma unroll 4
    for (int it = 0; it < 64; ++it) {
        const int slot = it % 4;                  // static under unroll-4
        float4 E0 = e0[slot], E1 = e1[slot];
        // prefetch round it+4 (reads past 255 land in padded tbl region)
        e0[slot] = t0[(ROFF + it + 4) * 128];
        e1[slot] = t0[(ROFF + it + 4) * 128 + 1];

        int ij0 = __float_as_int(E0.z);
        int a0 = ij0 & 0xffff, b0 = ij0 >> 16;
        int ij1 = __float_as_int(E1.z);
        int a1 = ij1 & 0xffff, b1 = ij1 >> 16;

        float4 ra0 = buf[a0], rb0 = buf[b0];
        float4 ra1 = buf[a1], rb1 = buf[b1];
        float4 na0, nb0, na1, nb1;
        na0.x = E0.x * ra0.x - E0.y * rb0.x;
        na0.y = E0.x * ra0.y - E0.y * rb0.y;
        na0.z = E0.x * ra0.z - E0.y * rb0.z;
        na0.w = E0.x * ra0.w - E0.y * rb0.w;
        nb0.x = E0.y * ra0.x + E0.x * rb0.x;
        nb0.y = E0.y * ra0.y + E0.x * rb0.y;
        nb0.z = E0.y * ra0.z + E0.x * rb0.z;
        nb0.w = E0.y * ra0.w + E0.x * rb0.w;
        na1.x = E1.x * ra1.x - E1.y * rb1.x;
        na1.y = E1.x * ra1.y - E1.y * rb1.y;
        na1.z = E1.x * ra1.z - E1.y * rb1.z;
        na1.w = E1.x * ra1.w - E1.y * rb1.w;
        nb1.x = E1.y * ra1.x + E1.x * rb1.x;
        nb1.y = E1.y * ra1.y + E1.x * rb1.y;
        nb1.z = E1.y * ra1.z + E1.x * rb1.z;
        nb1.w = E1.y * ra1.w + E1.x * rb1.w;
        buf[a0] = na0; buf[b0] = nb0;
        buf[a1] = na1; buf[b1] = nb1;
    }
}

__global__ void k_rot(const float4* __restrict__ tbl, float* __restrict__ Rg) {
    __shared__ float4 buf[256];                  // 4 columns of the matrix
    int l   = threadIdx.x;                       // 0..63, one wave per block
    int grp = blockIdx.y;                        // 0..3
    int c0  = blockIdx.x * 4;                    // this block's 4 columns
#pragma unroll
    for (int q = 0; q < 4; ++q) {
        int m = l * 4 + q;
        float4 v = make_float4(0.f, 0.f, 0.f, 0.f);
        if (m == c0)     v.x = 1.f;
        if (m == c0 + 1) v.y = 1.f;
        if (m == c0 + 2) v.z = 1.f;
        if (m == c0 + 3) v.w = 1.f;
        buf[m] = v;                              // identity columns
    }
    const float4* t0 = tbl + 2 * l;              // this lane owns pairs 2l, 2l+1
    if      (grp == 0) rot_rounds64<0>(t0, buf);
    else if (grp == 1) rot_rounds64<64>(t0, buf);
    else if (grp == 2) rot_rounds64<128>(t0, buf);
    else               rot_rounds64<192>(t0, buf);

    float* Rout = Rg + grp * (256 * 256);
#pragma unroll
    for (int q = 0; q < 4; ++q) {
        int m = l * 4 + q;
        *(float4*)(Rout + m * 256 + c0) = buf[m];
    }
}

// ---------------------------------------------------------------------------
// K3: batched merge: dst[p] = src[2p+1] * src[2p]  (256x256 each).
// blockIdx.y = p.  128 blocks x 128 threads per product, float4 wide.
// Used twice: (Rg -> M, y=2) then (M -> R, y=1).
// ---------------------------------------------------------------------------
__global__ void k_merge(const float* __restrict__ src, float* __restrict__ dst) {
    const float* A = src + blockIdx.y * (2 * 65536);   // applied first
    const float* B = A + 65536;                        // applied second (left)
    float* D = dst + blockIdx.y * 65536;
    int idx = blockIdx.x * 128 + threadIdx.x;
    int i  = __builtin_amdgcn_readfirstlane(idx >> 6); // wave-uniform row
    int j4 = (idx & 63) * 4;
    float ax = 0.f, ay = 0.f, az = 0.f, aw = 0.f;
#pragma unroll 8
    for (int k = 0; k < 256; ++k) {
        float  s = B[i * 256 + k];                     // scalar (SMEM) load
        float4 b = *(const float4*)(A + k * 256 + j4); // coalesced
        ax += s * b.x; ay += s * b.y; az += s * b.z; aw += s * b.w;
    }
    *(float4*)(D + i * 256 + j4) = make_float4(ax, ay, az, aw);
}

// ---------------------------------------------------------------------------
// K4: out = R * X  (256x256 @ 256x8192), fp32 vector GEMM.
// Block: 512 threads = 8 waves; block tile 64 rows x 128 cols.
// Wave w owns rows iw..iw+7 (A via wave-uniform scalar loads -> SMEM pipe,
// zero LDS/VALU cost).  X staged in double-buffered LDS via global_load_lds
// (width 16); each lane reads 1 x ds_read_b64 per k for 16 FMAs ->
// VALU-saturated (~6.8 us floor), not LDS-bound.
// Grid (64,4) = 256 blocks, X re-read = 4x = 32 MB through L2.
// ---------------------------------------------------------------------------
__global__ __launch_bounds__(512) void k_gemm(const float* __restrict__ R,
                                              const float* __restrict__ X,
                                              float* __restrict__ out) {
    __shared__ __align__(16) float Xs[2][32][128];   // 2 x 16 KB k-chunks
    int t  = threadIdx.x;
    int w  = t >> 6;                                 // wave 0..7
    int l  = t & 63;
    int n0 = blockIdx.x * 128;                       // 64 col-groups
    int m0 = blockIdx.y * 64;                        // 4 row-groups
    int iw = __builtin_amdgcn_readfirstlane(m0 + w * 8);
    const float* Ra = R + iw * 256;                  // wave's 8 A-rows

    float2 acc[8];
#pragma unroll
    for (int r = 0; r < 8; ++r) acc[r] = make_float2(0.f, 0.f);

    // stage one 32k x 128col chunk: each wave stages 4 k-rows via 2
    // global_load_lds issues (each issue = 2 rows: lane l -> lds base + l*16)
    auto stage = [&](int bi, int kc) {
        int k0  = kc * 32;
        int kkb = w * 4;
#pragma unroll
        for (int p = 0; p < 2; ++p) {
            int row = kkb + p * 2 + (l >> 5);
            int col = (l & 31) * 4;
            const float* src = X + (size_t)(k0 + row) * NB + n0 + col;
            __builtin_amdgcn_global_load_lds(
                (const __attribute__((address_space(1))) unsigned int*)src,
                (__attribute__((address_space(3))) unsigned int*)&Xs[bi][kkb + p * 2][0],
                16, 0, 0);
        }
    };

    stage(0, 0);
    __syncthreads();                                  // implies vmcnt(0) drain
    int buf = 0;
    for (int kc = 0; kc < 8; ++kc) {
        if (kc < 7) stage(buf ^ 1, kc + 1);           // prefetch next chunk
#pragma unroll
        for (int k4 = 0; k4 < 8; ++k4) {              // 4-k sub-chunks
            float4 ar[8];
#pragma unroll
            for (int r = 0; r < 8; ++r)               // uniform addr -> s_load
                ar[r] = *(const float4*)(Ra + r * 256 + kc * 32 + k4 * 4);
#pragma unroll
            for (int q = 0; q < 4; ++q) {
                float2 x = *(const float2*)&Xs[buf][k4 * 4 + q][l * 2];
#pragma unroll
                for (int r = 0; r < 8; ++r) {
                    float av = (q == 0) ? ar[r].x : (q == 1) ? ar[r].y
                             : (q == 2) ? ar[r].z : ar[r].w;
                    acc[r].x += av * x.x;
                    acc[r].y += av * x.y;
                }
            }
        }
        __syncthreads();                              // staged chunk now visible
        buf ^= 1;
    }
#pragma unroll
    for (int r = 0; r < 8; ++r) {
        *(float2*)(out + (size_t)(iw + r) * NB + n0 + l * 2) = acc[r];
    }
}

// ---------------------------------------------------------------------------
extern "C" void kernel_launch(void* const* d_in, const int* in_sizes, int n_in,
                              void* d_out, int out_size, void* d_ws, size_t ws_size,
                              hipStream_t stream) {
    const float* X      = (const float*)d_in[0];
    const float* thetas = (const float*)d_in[1];
    float* out = (float*)d_out;
    char*  ws  = (char*)d_ws;

    float4* tbl = (float4*)ws;
    float*  Rg  = (float*)(ws + 540672);
    float*  M   = (float*)(ws + 1589248);
    float*  R   = (float*)(ws + 2113536);

    k_prep <<<dim3(132),    dim3(256), 0, stream>>>(thetas, tbl);
    k_rot  <<<dim3(64, 4),  dim3(64),  0, stream>>>(tbl, Rg);
    k_merge<<<dim3(128, 2), dim3(128), 0, stream>>>(Rg, M);   // M0=R1*R0, M1=R3*R2
    k_merge<<<dim3(128, 1), dim3(128), 0, stream>>>(M, R);    // R = M1*M0
    k_gemm <<<dim3(64, 4),  dim3(512), 0, stream>>>(R, X, out);
}